// Round 21
// baseline (435.934 us; speedup 1.0000x reference)
//
#include <hip/hip_runtime.h>

typedef __bf16 bf16;
typedef bf16 bf16x4 __attribute__((ext_vector_type(4)));
typedef bf16 bf16x8 __attribute__((ext_vector_type(8)));
typedef float f32x4 __attribute__((ext_vector_type(4)));

static constexpr int BATCH = 16;
static constexpr int SEQ   = 2048;  // N
static constexpr int DH    = 512;   // H (== M)
static constexpr int ROWS  = BATCH * SEQ;  // 32768

__device__ __forceinline__ f32x4 mfma16(bf16x8 a, bf16x8 b, f32x4 c) {
    return __builtin_amdgcn_mfma_f32_16x16x32_bf16(a, b, c, 0, 0, 0);
}

// async global->LDS, 16B per lane. dst must be wave-uniform base (HW adds lane*16).
__device__ __forceinline__ void gl_lds16(const void* g, void* l) {
    __builtin_amdgcn_global_load_lds((const __attribute__((address_space(1))) void*)g,
                                     (__attribute__((address_space(3))) void*)l, 16, 0, 0);
}

// -------- 5 weights [K=512][N=512] fp32 -> [N][K] bf16 (h-cvt now fused in tqk) --------
__global__ void cvt_w5_kernel(const float* __restrict__ w0, const float* __restrict__ w1,
                              const float* __restrict__ w2, const float* __restrict__ w3,
                              const float* __restrict__ w4, bf16* __restrict__ wout) {
    const int b = blockIdx.x;           // 0..5119
    const int t = b >> 10;
    const float* in = (t == 0) ? w0 : (t == 1) ? w1 : (t == 2) ? w2 : (t == 3) ? w3 : w4;
    int idx = (b & 1023) * 256 + threadIdx.x;  // idx = n*512 + k
    int n = idx >> 9, k = idx & 511;
    wout[t * 262144 + idx] = (bf16)in[k * 512 + n];
}

// ---------------- fused t/q/k GEMM over fp32 X: 3 weights, one X panel ----------------
// R21: X staged DIRECTLY from fp32 h via regs (8 f32x4 loads -> cvt -> 4 ds_write_b128),
// eliminating the 67MB hb round-trip. W via gl_lds as before. Counted-vmcnt:
// xwrite(t) auto-waits X(t) regs (W(t) stays in flight); after issuing
// xload(t+1)+wstage(t+1), vmcnt(12) retires exactly W(t). The ds_write address
// row*64+(tid&7)*8 with source block skb=(tid&7)^(row&7) reproduces the
// gl_lds16 swizzled layout bit-for-bit (verified algebraically).
__global__ __launch_bounds__(256, 2)
void gemm_tqk_kernel(const float* __restrict__ Xf,
                     const bf16* __restrict__ Wt0, const bf16* __restrict__ Wt1,
                     const bf16* __restrict__ Wt2,
                     const float* __restrict__ b0, const float* __restrict__ b1,
                     const float* __restrict__ b2,
                     bf16* __restrict__ Y0, bf16* __restrict__ Y1, bf16* __restrict__ Y2)
{
    __shared__ bf16 smem[32768];   // 64KB: Xl buf0/1 (16KB ea), Wl buf0/1 (16KB ea)

    const int tid = threadIdx.x;
    const int lane = tid & 63, wid = tid >> 6;
    const int wr = wid >> 1, wc = wid & 1;
    const int id = blockIdx.x;
    const int r0 = (((id >> 5) << 3) + (id & 7)) * 128;  // row-panel
    const int c0 = ((id >> 3) & 3) * 128;                // col-tile
    const int lrow = lane & 15, lhi = lane >> 4;

    const int srow = tid >> 3;
    const int skb  = (tid & 7) ^ (srow & 7);
    const int sdst = wid * 512;

    for (int w = 0; w < 3; ++w) {
        const bf16* Wt = (w == 0) ? Wt0 : (w == 1) ? Wt1 : Wt2;
        const float* bias = (w == 0) ? b0 : (w == 1) ? b1 : b2;
        bf16* Y = (w == 0) ? Y0 : (w == 1) ? Y1 : Y2;

        f32x4 xr[4][2];   // one K-step of X in regs (32 VGPR)
        auto xload = [&](int kc) {
            const float* xs = Xf + (size_t)r0 * 512 + kc * 64;
            #pragma unroll
            for (int c = 0; c < 4; ++c) {
                const int row = c * 32 + srow;
                xr[c][0] = *reinterpret_cast<const f32x4*>(xs + (size_t)row * 512 + skb * 8);
                xr[c][1] = *reinterpret_cast<const f32x4*>(xs + (size_t)row * 512 + skb * 8 + 4);
            }
        };
        auto xwrite = [&](int buf) {
            bf16* Xl = smem + buf * 8192;
            #pragma unroll
            for (int c = 0; c < 4; ++c) {
                const int row = c * 32 + srow;
                bf16x8 v;
                #pragma unroll
                for (int jj = 0; jj < 4; ++jj) {
                    v[jj]     = (bf16)xr[c][0][jj];
                    v[4 + jj] = (bf16)xr[c][1][jj];
                }
                *reinterpret_cast<bf16x8*>(&Xl[row * 64 + (tid & 7) * 8]) = v;
            }
        };
        auto wstage = [&](int buf, int kc) {
            const bf16* wsrc = Wt + (size_t)c0 * 512 + kc * 64;
            bf16* Wl = smem + 16384 + buf * 8192;
            #pragma unroll
            for (int c = 0; c < 4; ++c) {
                const int row = c * 32 + srow;
                gl_lds16(wsrc + (size_t)row * 512 + skb * 8, Wl + c * 2048 + sdst);
            }
        };

        f32x4 acc[4][4] = {};

        xload(0);
        wstage(0, 0);

        for (int t = 0; t < 8; ++t) {
            const int buf = t & 1;
            xwrite(buf);                 // auto-waits X(t) regs; W(t) stays in flight
            if (t + 1 < 8) {
                xload(t + 1);            // reuse xr (reg WAR after xwrite reads)
                wstage(buf ^ 1, t + 1);
                // retire exactly W(t) (oldest 4); leave X(t+1)+W(t+1)=12 in flight
                asm volatile("s_waitcnt vmcnt(12) lgkmcnt(0)" ::: "memory");
            } else {
                asm volatile("s_waitcnt vmcnt(0) lgkmcnt(0)" ::: "memory");
            }
            __builtin_amdgcn_s_barrier();    // B1: buf fully staged, published
            __builtin_amdgcn_sched_barrier(0);

            const bf16* Xl = smem + buf * 8192;
            const bf16* Wl = smem + 16384 + buf * 8192;
            #pragma unroll
            for (int kk = 0; kk < 2; ++kk) {
                bf16x8 af[4], bfr[4];
                const int kb = kk * 4 + lhi;
                #pragma unroll
                for (int tt = 0; tt < 4; ++tt) {
                    const int ra = wr * 64 + tt * 16 + lrow;
                    af[tt] = *reinterpret_cast<const bf16x8*>(&Xl[ra * 64 + ((kb ^ (ra & 7)) * 8)]);
                }
                #pragma unroll
                for (int tt = 0; tt < 4; ++tt) {
                    const int rb = wc * 64 + tt * 16 + lrow;
                    bfr[tt] = *reinterpret_cast<const bf16x8*>(&Wl[rb * 64 + ((kb ^ (rb & 7)) * 8)]);
                }
                #pragma unroll
                for (int i = 0; i < 4; ++i)
                    #pragma unroll
                    for (int j = 0; j < 4; ++j)
                        acc[i][j] = mfma16(af[i], bfr[j], acc[i][j]);
            }

            // B2: reads of buf retired -> next iter may write over buf (WAR)
            asm volatile("s_waitcnt lgkmcnt(0)" ::: "memory");
            __builtin_amdgcn_s_barrier();
            __builtin_amdgcn_sched_barrier(0);
        }

        #pragma unroll
        for (int i = 0; i < 4; ++i) {
            #pragma unroll
            for (int j = 0; j < 4; ++j) {
                const int col = c0 + wc * 64 + j * 16 + lrow;
                const float bb = bias[col];
                #pragma unroll
                for (int rg = 0; rg < 4; ++rg) {
                    const int r = r0 + wr * 64 + i * 16 + lhi * 4 + rg;
                    float y = acc[i][j][rg] + bb;
                    y = y > 0.f ? y : 0.f;
                    Y[(size_t)r * 512 + col] = (bf16)y;
                }
            }
        }
        // next w's prologue writes buf0, whose last reads retired at B2(t=6);
        // all waves are past B2(t=7) (barriers are collective) -> no race.
    }
}

// ---------------- GEMM: Y = relu(X[R,512] @ W[512,512] + b), LDS staged ----
// OMODE 1: also write transposed copy via LDS (coalesced bf16x8 stores).
// OMODE 2: fp32 out.
template <int OMODE>
__global__ __launch_bounds__(256, 2)
void gemm_relu_kernel(const bf16* __restrict__ X, const bf16* __restrict__ Wt,
                      const float* __restrict__ bias,
                      bf16* __restrict__ Y, bf16* __restrict__ Yt,
                      float* __restrict__ Yf)
{
    __shared__ bf16 smem[32768];   // 64KB; reused as transpose tile in epilogue

    const int tid = threadIdx.x;
    const int lane = tid & 63, wid = tid >> 6;
    const int wr = wid >> 1, wc = wid & 1;
    const int id = blockIdx.x;
    const int r0 = (((id >> 5) << 3) + (id & 7)) * 128;  // row-panel
    const int c0 = ((id >> 3) & 3) * 128;                // col-tile
    const int lrow = lane & 15, lhi = lane >> 4;

    const int srow = tid >> 3;
    const int skb  = (tid & 7) ^ (srow & 7);
    const int sdst = wid * 512;

    auto stage = [&](int buf, int kc) {
        const bf16* xs = X + (size_t)r0 * 512 + kc * 64;
        const bf16* ws = Wt + (size_t)c0 * 512 + kc * 64;
        bf16* Xl = smem + buf * 8192;
        bf16* Wl = smem + 16384 + buf * 8192;
        #pragma unroll
        for (int c = 0; c < 4; ++c) {
            const int row = c * 32 + srow;
            gl_lds16(xs + (size_t)row * 512 + skb * 8, Xl + c * 2048 + sdst);
        }
        #pragma unroll
        for (int c = 0; c < 4; ++c) {
            const int row = c * 32 + srow;
            gl_lds16(ws + (size_t)row * 512 + skb * 8, Wl + c * 2048 + sdst);
        }
    };

    f32x4 acc[4][4] = {};

    stage(0, 0);

    for (int t = 0; t < 8; ++t) {
        const int buf = t & 1;
        if (t + 1 < 8) {
            stage(buf ^ 1, t + 1);
            asm volatile("s_waitcnt vmcnt(8)" ::: "memory");
        } else {
            asm volatile("s_waitcnt vmcnt(0)" ::: "memory");
        }
        __builtin_amdgcn_s_barrier();
        __builtin_amdgcn_sched_barrier(0);

        const bf16* Xl = smem + buf * 8192;
        const bf16* Wl = smem + 16384 + buf * 8192;
        #pragma unroll
        for (int kk = 0; kk < 2; ++kk) {
            bf16x8 af[4], bfr[4];
            const int kb = kk * 4 + lhi;
            #pragma unroll
            for (int tt = 0; tt < 4; ++tt) {
                const int ra = wr * 64 + tt * 16 + lrow;
                af[tt] = *reinterpret_cast<const bf16x8*>(&Xl[ra * 64 + ((kb ^ (ra & 7)) * 8)]);
            }
            #pragma unroll
            for (int tt = 0; tt < 4; ++tt) {
                const int rb = wc * 64 + tt * 16 + lrow;
                bfr[tt] = *reinterpret_cast<const bf16x8*>(&Wl[rb * 64 + ((kb ^ (rb & 7)) * 8)]);
            }
            #pragma unroll
            for (int i = 0; i < 4; ++i)
                #pragma unroll
                for (int j = 0; j < 4; ++j)
                    acc[i][j] = mfma16(af[i], bfr[j], acc[i][j]);
        }

        asm volatile("s_waitcnt lgkmcnt(0)" ::: "memory");
        __builtin_amdgcn_s_barrier();
        __builtin_amdgcn_sched_barrier(0);
    }

    #pragma unroll
    for (int i = 0; i < 4; ++i) {
        #pragma unroll
        for (int j = 0; j < 4; ++j) {
            const int col = c0 + wc * 64 + j * 16 + lrow;
            const float bb = bias[col];
            #pragma unroll
            for (int rg = 0; rg < 4; ++rg) {
                const int r = r0 + wr * 64 + i * 16 + lhi * 4 + rg;
                float y = acc[i][j][rg] + bb;
                y = y > 0.f ? y : 0.f;
                if (OMODE == 2) {
                    Yf[(size_t)r * 512 + col] = y;
                } else {
                    Y[(size_t)r * 512 + col] = (bf16)y;
                    if (OMODE == 1) {
                        smem[(wc * 64 + j * 16 + lrow) * 136
                             + (wr * 64 + i * 16 + lhi * 4 + rg)] = (bf16)y;
                    }
                }
            }
        }
    }

    if (OMODE == 1) {
        __syncthreads();
        const int hr = tid >> 1, half = tid & 1;
        const size_t obase = ((size_t)(r0 >> 11) * 512 + c0 + hr) * 2048
                             + (r0 & 2047) + half * 64;
        #pragma unroll
        for (int c = 0; c < 8; ++c) {
            bf16x8 v = *reinterpret_cast<const bf16x8*>(&smem[hr * 136 + half * 64 + c * 8]);
            *reinterpret_cast<bf16x8*>(&Yt[obase + c * 8]) = v;
        }
    }
}

// ---------------- fused attention (R19-exact, ~300us) ----------------
// max==0 softmax (q,k>=0, A in [0,1) => scores<=0): p = exp(x) directly,
// l per-lane, reduced once at epilogue. KVBLK=128 (16 iters). K single-buffered
// (128KB), staged after B1. P_lds stride 128 + 16B-block XOR swizzle.
// s_setprio(1) around both MFMA clusters (T5).
__global__ __launch_bounds__(512, 1)
void attn_kernel(const bf16* __restrict__ Q, const bf16* __restrict__ K,
                 const bf16* __restrict__ Vt, const bf16* __restrict__ V,
                 const float* __restrict__ A, bf16* __restrict__ O)
{
    __shared__ bf16 K_lds[128 * 512];     // 128KB, XOR-swizzled rows, single buffer
    __shared__ bf16 P_lds[64 * 128];      // 16KB, stride 128, XOR-swizzled 16B blocks
    __shared__ float sump_lds[2][64];     // per-strip l partials (epilogue only)

    const int tid = threadIdx.x;
    const int lane = tid & 63, wid = tid >> 6;
    const int wr = wid >> 1, wc = wid & 1;
    const int lrow = lane & 15, lhi = lane >> 4;

    // XCD x handles batches {2x, 2x+1}
    const int id = blockIdx.x;
    const int xcd = id & 7, j = id >> 3;
    const int bb = 2 * xcd + (j >> 5);
    const int n0 = (j & 31) * 64;
    const int srow_base = wr * 16 + lhi * 4;

    const bf16* Kbase  = K + (size_t)bb * SEQ * DH;
    const bf16* Vtbase = Vt + (size_t)bb * DH * SEQ;

    // stage K[0]: 128 rows, 16 per wave
    #pragma unroll
    for (int c = 0; c < 16; ++c) {
        const int row = wid * 16 + c;
        gl_lds16(Kbase + (size_t)row * DH + ((lane ^ (row & 7)) * 8), &K_lds[row * 512]);
    }

    // Q resident: rows n0 + wr*16 + lrow (wc pair loads same rows). 64 VGPR.
    bf16x8 qf[16];
    {
        const bf16* qp = Q + (size_t)(bb * SEQ + n0 + wr * 16 + lrow) * DH + lhi * 8;
        #pragma unroll
        for (int kk = 0; kk < 16; ++kk)
            qf[kk] = *reinterpret_cast<const bf16x8*>(qp + kk * 32);
    }

    float l_part[4] = {};      // per-lane denominator partials (rows srow_base+rg)
    f32x4 acc[4][4] = {};      // [q-row-tile][h-tile of this wave's 64-col slice]

    __syncthreads();  // K[0] drained + published

    for (int it = 0; it < 16; ++it) {
        const int m0 = it * 128;

        // A for this iter (consumed after QK^T). 16 loads.
        float av[16];  // [sc*4 + rg]
        {
            const float* ap = A + ((size_t)bb * SEQ + n0 + srow_base) * SEQ + m0 + wc * 64 + lrow;
            #pragma unroll
            for (int sc = 0; sc < 4; ++sc)
                #pragma unroll
                for (int rg = 0; rg < 4; ++rg)
                    av[sc * 4 + rg] = ap[(size_t)rg * SEQ + sc * 16];
        }

        // ---- QK^T: S[16 rows x 64-col strip] from K_lds (4 indep chains) ----
        f32x4 s[4] = {};
        {
            __builtin_amdgcn_s_setprio(1);
            #pragma unroll
            for (int kk = 0; kk < 16; ++kk) {
                const int ks = kk * 4 + lhi;
                #pragma unroll
                for (int sc = 0; sc < 4; ++sc) {
                    const int kr = wc * 64 + sc * 16 + lrow;
                    bf16x8 kf = *reinterpret_cast<const bf16x8*>(
                        &K_lds[kr * 512 + ((ks ^ (kr & 7)) * 8)]);
                    s[sc] = mfma16(qf[kk], kf, s[sc]);
                }
            }
            __builtin_amdgcn_s_setprio(0);
        }

        // ---- p = exp(score * -A) (max==0); P -> LDS (swizzled); l accumulate ----
        #pragma unroll
        for (int sc = 0; sc < 4; ++sc) {
            #pragma unroll
            for (int rg = 0; rg < 4; ++rg) {
                const float p = __expf(s[sc][rg] * (-av[sc * 4 + rg]));
                const int row = srow_base + rg;
                const int blk = wc * 8 + sc * 2 + (lrow >> 3);   // col>>3
                P_lds[row * 128 + ((blk ^ (row & 7)) * 8) + (lrow & 7)] = (bf16)p;
                l_part[rg] += p;
            }
        }

        // B1: lgkm-only — P writes + K reads retired; VMEM stays in flight
        asm volatile("s_waitcnt lgkmcnt(0)" ::: "memory");
        __builtin_amdgcn_s_barrier();
        __builtin_amdgcn_sched_barrier(0);

        // stage K[it+1] into the SAME buffer (WAR-safe: all K reads retired at
        // B1). Completion: vf loads below issued AFTER these; PV's vf wait
        // (in-order vmcnt) forces stage completion; B2 publishes block-wide.
        if (it + 1 < 16) {
            #pragma unroll
            for (int c = 0; c < 16; ++c) {
                const int row = wid * 16 + c;
                gl_lds16(Kbase + (size_t)(m0 + 128 + row) * DH + ((lane ^ (row & 7)) * 8),
                         &K_lds[row * 512]);
            }
        }

        // ---- PV: P (LDS, swizzled) x Vt (JIT regs, per-kc double-buffer) ----
        {
            const bf16* vp = Vtbase + (size_t)(wid * 64 + lrow) * SEQ + m0 + lhi * 8;
            bf16x8 vfk[2][4];
            #pragma unroll
            for (int ht = 0; ht < 4; ++ht)
                vfk[0][ht] = *reinterpret_cast<const bf16x8*>(vp + (size_t)(ht * 16) * SEQ);
            #pragma unroll
            for (int kc = 0; kc < 4; ++kc) {
                if (kc + 1 < 4) {
                    #pragma unroll
                    for (int ht = 0; ht < 4; ++ht)
                        vfk[(kc + 1) & 1][ht] = *reinterpret_cast<const bf16x8*>(
                            vp + (size_t)(ht * 16) * SEQ + (kc + 1) * 32);
                }
                __builtin_amdgcn_s_setprio(1);
                #pragma unroll
                for (int t = 0; t < 4; ++t) {
                    const int prow = t * 16 + lrow;
                    const bf16x8 pf = *reinterpret_cast<const bf16x8*>(
                        &P_lds[prow * 128 + (((kc * 4 + lhi) ^ (prow & 7)) * 8)]);
                    #pragma unroll
                    for (int ht = 0; ht < 4; ++ht)
                        acc[t][ht] = mfma16(pf, vfk[kc & 1][ht], acc[t][ht]);
                }
                __builtin_amdgcn_s_setprio(0);
            }
        }

        // B2: lgkm-only — P reads retired (WAR for next writes); K[it+1] stage
        // complete per-wave (via vf in-order waits) -> published block-wide.
        asm volatile("s_waitcnt lgkmcnt(0)" ::: "memory");
        __builtin_amdgcn_s_barrier();
        __builtin_amdgcn_sched_barrier(0);
    }

    // ---- epilogue: reduce l over the 16 lrow lanes per strip, combine strips ----
    #pragma unroll
    for (int rg = 0; rg < 4; ++rg) {
        float sv = l_part[rg];
        sv += __shfl_xor(sv, 1);
        sv += __shfl_xor(sv, 2);
        sv += __shfl_xor(sv, 4);
        sv += __shfl_xor(sv, 8);
        if (lrow == 0) sump_lds[wc][srow_base + rg] = sv;
    }
    __syncthreads();

    // ---- /l, +V, store ----
    #pragma unroll
    for (int t = 0; t < 4; ++t) {
        #pragma unroll
        for (int rg = 0; rg < 4; ++rg) {
            const int row = t * 16 + lhi * 4 + rg;
            const float inv = 1.f / (sump_lds[0][row] + sump_lds[1][row]);
            const size_t rbase = (size_t)(bb * SEQ + n0 + row) * DH;
            #pragma unroll
            for (int ht = 0; ht < 4; ++ht) {
                const int col = wid * 64 + ht * 16 + lrow;
                const float vv = (float)V[rbase + col];
                O[rbase + col] = (bf16)(acc[t][ht][rg] * inv + vv);
            }
        }
    }
}

extern "C" void kernel_launch(void* const* d_in, const int* in_sizes, int n_in,
                              void* d_out, int out_size, void* d_ws, size_t ws_size,
                              hipStream_t stream) {
    const float* A    = (const float*)d_in[0];
    const float* h    = (const float*)d_in[1];
    const float* Wv1  = (const float*)d_in[2];
    const float* bv1  = (const float*)d_in[3];
    const float* Wv2  = (const float*)d_in[4];
    const float* bv2  = (const float*)d_in[5];
    const float* Wk   = (const float*)d_in[6];   // NOTE: Wk before Wq in dict order
    const float* bk   = (const float*)d_in[7];
    const float* Wq   = (const float*)d_in[8];
    const float* bq   = (const float*)d_in[9];
    const float* Wout = (const float*)d_in[10];
    const float* bout = (const float*)d_in[11];
    float* out = (float*)d_out;

    char* ws = (char*)d_ws;
    const size_t SZ = (size_t)ROWS * 512 * sizeof(bf16);  // 33.5 MB
    bf16* vtb  = (bf16*)(ws + 0 * SZ);  // v transposed [B][H][N] (hb slot, now free)
    bf16* tb   = (bf16*)(ws + 1 * SZ);  // t; dead after v-GEMM -> ob aliases it
    bf16* qb   = (bf16*)(ws + 2 * SZ);
    bf16* kb   = (bf16*)(ws + 3 * SZ);
    bf16* vb   = (bf16*)(ws + 4 * SZ);
    bf16* wbase = (bf16*)(ws + 5 * SZ); // 5 x 512KB bf16 weights
    bf16* Wv1t  = wbase + 0 * 262144;
    bf16* Wv2t  = wbase + 1 * 262144;
    bf16* Wqt   = wbase + 2 * 262144;
    bf16* Wkt   = wbase + 3 * 262144;
    bf16* Woutt = wbase + 4 * 262144;
    bf16* ob  = tb;  // attention output; tb dead after v-GEMM

    cvt_w5_kernel<<<5120, 256, 0, stream>>>(Wv1, Wv2, Wq, Wk, Wout, wbase);

    // t, q, k in ONE launch, X staged directly from fp32 h (no hb round-trip)
    gemm_tqk_kernel<<<1024, 256, 0, stream>>>(h, Wv1t, Wqt, Wkt, bv1, bq, bk,
                                              tb, qb, kb);

    // v = relu(t @ Wv2 + b), plus coalesced transposed copy vtb
    gemm_relu_kernel<1><<<1024, 256, 0, stream>>>(tb, Wv2t, bv2, vb, vtb, nullptr);

    attn_kernel<<<dim3(512), 512, 0, stream>>>(qb, kb, vtb, vb, A, ob);

    gemm_relu_kernel<2><<<1024, 256, 0, stream>>>(ob, Woutt, bout, nullptr, nullptr, out);
}

// Round 22
// 412.376 us; speedup vs baseline: 1.0571x; 1.0571x over previous
//
#include <hip/hip_runtime.h>

typedef __bf16 bf16;
typedef bf16 bf16x4 __attribute__((ext_vector_type(4)));
typedef bf16 bf16x8 __attribute__((ext_vector_type(8)));
typedef float f32x4 __attribute__((ext_vector_type(4)));

static constexpr int BATCH = 16;
static constexpr int SEQ   = 2048;  // N
static constexpr int DH    = 512;   // H (== M)
static constexpr int ROWS  = BATCH * SEQ;  // 32768

__device__ __forceinline__ f32x4 mfma16(bf16x8 a, bf16x8 b, f32x4 c) {
    return __builtin_amdgcn_mfma_f32_16x16x32_bf16(a, b, c, 0, 0, 0);
}

// async global->LDS, 16B per lane. dst must be wave-uniform base (HW adds lane*16).
__device__ __forceinline__ void gl_lds16(const void* g, void* l) {
    __builtin_amdgcn_global_load_lds((const __attribute__((address_space(1))) void*)g,
                                     (__attribute__((address_space(3))) void*)l, 16, 0, 0);
}

// -------- fused conversions: h fp32->bf16 + 5 weights fp32->[N][K] bf16 --------
__global__ void cvt_all_kernel(const float* __restrict__ h,
                               const float* __restrict__ w0, const float* __restrict__ w1,
                               const float* __restrict__ w2, const float* __restrict__ w3,
                               const float* __restrict__ w4,
                               bf16* __restrict__ hb, bf16* __restrict__ wout) {
    const int b = blockIdx.x;
    if (b < 4096) {
        const int n4 = ROWS * 512 / 4;
        int i = b * 256 + threadIdx.x;
        const int stride = 4096 * 256;
        for (; i < n4; i += stride) {
            f32x4 f = *reinterpret_cast<const f32x4*>(h + (size_t)i * 4);
            bf16x4 o;
            o[0] = (bf16)f[0]; o[1] = (bf16)f[1]; o[2] = (bf16)f[2]; o[3] = (bf16)f[3];
            *reinterpret_cast<bf16x4*>(hb + (size_t)i * 4) = o;
        }
    } else {
        const int bb = b - 4096;
        const int t = bb >> 10;
        const float* in = (t == 0) ? w0 : (t == 1) ? w1 : (t == 2) ? w2 : (t == 3) ? w3 : w4;
        int idx = (bb & 1023) * 256 + threadIdx.x;  // idx = n*512 + k
        int n = idx >> 9, k = idx & 511;
        wout[t * 262144 + idx] = (bf16)in[k * 512 + n];
    }
}

// ---------------- fused t/q/k GEMM: 3 weights over one X panel ----------------
// Per block, loop w=0..2 reusing the X row-panel (2nd/3rd stage hits L2,
// saves 2 launches + 67MB HBM). XCD-coherent swizzle. Counted-vmcnt
// double-barrier pipeline per K-step.
__global__ __launch_bounds__(256, 2)
void gemm_tqk_kernel(const bf16* __restrict__ X,
                     const bf16* __restrict__ Wt0, const bf16* __restrict__ Wt1,
                     const bf16* __restrict__ Wt2,
                     const float* __restrict__ b0, const float* __restrict__ b1,
                     const float* __restrict__ b2,
                     bf16* __restrict__ Y0, bf16* __restrict__ Y1, bf16* __restrict__ Y2)
{
    __shared__ bf16 smem[32768];   // 64KB: Xl buf0/1, Wl buf0/1 (16KB each)

    const int tid = threadIdx.x;
    const int lane = tid & 63, wid = tid >> 6;
    const int wr = wid >> 1, wc = wid & 1;
    const int id = blockIdx.x;
    const int r0 = (((id >> 5) << 3) + (id & 7)) * 128;  // row-panel
    const int c0 = ((id >> 3) & 3) * 128;                // col-tile
    const int lrow = lane & 15, lhi = lane >> 4;

    const int srow = tid >> 3;
    const int skb  = (tid & 7) ^ (srow & 7);
    const int sdst = wid * 512;

    for (int w = 0; w < 3; ++w) {
        const bf16* Wt = (w == 0) ? Wt0 : (w == 1) ? Wt1 : Wt2;
        const float* bias = (w == 0) ? b0 : (w == 1) ? b1 : b2;
        bf16* Y = (w == 0) ? Y0 : (w == 1) ? Y1 : Y2;

        auto stage = [&](int buf, int kc) {
            const bf16* xs = X + (size_t)r0 * 512 + kc * 64;
            const bf16* ws = Wt + (size_t)c0 * 512 + kc * 64;
            bf16* Xl = smem + buf * 8192;
            bf16* Wl = smem + 16384 + buf * 8192;
            #pragma unroll
            for (int c = 0; c < 4; ++c) {
                const int row = c * 32 + srow;
                gl_lds16(xs + (size_t)row * 512 + skb * 8, Xl + c * 2048 + sdst);
            }
            #pragma unroll
            for (int c = 0; c < 4; ++c) {
                const int row = c * 32 + srow;
                gl_lds16(ws + (size_t)row * 512 + skb * 8, Wl + c * 2048 + sdst);
            }
        };

        f32x4 acc[4][4] = {};

        stage(0, 0);

        for (int t = 0; t < 8; ++t) {
            const int buf = t & 1;
            if (t + 1 < 8) {
                stage(buf ^ 1, t + 1);
                asm volatile("s_waitcnt vmcnt(8)" ::: "memory");
            } else {
                asm volatile("s_waitcnt vmcnt(0)" ::: "memory");
            }
            __builtin_amdgcn_s_barrier();
            __builtin_amdgcn_sched_barrier(0);

            const bf16* Xl = smem + buf * 8192;
            const bf16* Wl = smem + 16384 + buf * 8192;
            #pragma unroll
            for (int kk = 0; kk < 2; ++kk) {
                bf16x8 af[4], bfr[4];
                const int kb = kk * 4 + lhi;
                #pragma unroll
                for (int tt = 0; tt < 4; ++tt) {
                    const int ra = wr * 64 + tt * 16 + lrow;
                    af[tt] = *reinterpret_cast<const bf16x8*>(&Xl[ra * 64 + ((kb ^ (ra & 7)) * 8)]);
                }
                #pragma unroll
                for (int tt = 0; tt < 4; ++tt) {
                    const int rb = wc * 64 + tt * 16 + lrow;
                    bfr[tt] = *reinterpret_cast<const bf16x8*>(&Wl[rb * 64 + ((kb ^ (rb & 7)) * 8)]);
                }
                #pragma unroll
                for (int i = 0; i < 4; ++i)
                    #pragma unroll
                    for (int j = 0; j < 4; ++j)
                        acc[i][j] = mfma16(af[i], bfr[j], acc[i][j]);
            }

            asm volatile("s_waitcnt lgkmcnt(0)" ::: "memory");
            __builtin_amdgcn_s_barrier();
            __builtin_amdgcn_sched_barrier(0);
        }

        #pragma unroll
        for (int i = 0; i < 4; ++i) {
            #pragma unroll
            for (int j = 0; j < 4; ++j) {
                const int col = c0 + wc * 64 + j * 16 + lrow;
                const float bb = bias[col];
                #pragma unroll
                for (int rg = 0; rg < 4; ++rg) {
                    const int r = r0 + wr * 64 + i * 16 + lhi * 4 + rg;
                    float y = acc[i][j][rg] + bb;
                    y = y > 0.f ? y : 0.f;
                    Y[(size_t)r * 512 + col] = (bf16)y;
                }
            }
        }
        // no barrier needed before next w: next stage writes buf0, whose last
        // reads retired at B2(step6) — all waves are past B2(step7).
    }
}

// ---------------- GEMM: Y = relu(X[R,512] @ W[512,512] + b), LDS staged ----
// OMODE 1: also write transposed copy via LDS (coalesced bf16x8 stores).
// OMODE 2: fp32 out.
template <int OMODE>
__global__ __launch_bounds__(256, 2)
void gemm_relu_kernel(const bf16* __restrict__ X, const bf16* __restrict__ Wt,
                      const float* __restrict__ bias,
                      bf16* __restrict__ Y, bf16* __restrict__ Yt,
                      float* __restrict__ Yf)
{
    __shared__ bf16 smem[32768];   // 64KB; reused as transpose tile in epilogue

    const int tid = threadIdx.x;
    const int lane = tid & 63, wid = tid >> 6;
    const int wr = wid >> 1, wc = wid & 1;
    const int id = blockIdx.x;
    const int r0 = (((id >> 5) << 3) + (id & 7)) * 128;  // row-panel
    const int c0 = ((id >> 3) & 3) * 128;                // col-tile
    const int lrow = lane & 15, lhi = lane >> 4;

    const int srow = tid >> 3;
    const int skb  = (tid & 7) ^ (srow & 7);
    const int sdst = wid * 512;

    auto stage = [&](int buf, int kc) {
        const bf16* xs = X + (size_t)r0 * 512 + kc * 64;
        const bf16* ws = Wt + (size_t)c0 * 512 + kc * 64;
        bf16* Xl = smem + buf * 8192;
        bf16* Wl = smem + 16384 + buf * 8192;
        #pragma unroll
        for (int c = 0; c < 4; ++c) {
            const int row = c * 32 + srow;
            gl_lds16(xs + (size_t)row * 512 + skb * 8, Xl + c * 2048 + sdst);
        }
        #pragma unroll
        for (int c = 0; c < 4; ++c) {
            const int row = c * 32 + srow;
            gl_lds16(ws + (size_t)row * 512 + skb * 8, Wl + c * 2048 + sdst);
        }
    };

    f32x4 acc[4][4] = {};

    stage(0, 0);

    for (int t = 0; t < 8; ++t) {
        const int buf = t & 1;
        if (t + 1 < 8) {
            stage(buf ^ 1, t + 1);
            asm volatile("s_waitcnt vmcnt(8)" ::: "memory");
        } else {
            asm volatile("s_waitcnt vmcnt(0)" ::: "memory");
        }
        __builtin_amdgcn_s_barrier();
        __builtin_amdgcn_sched_barrier(0);

        const bf16* Xl = smem + buf * 8192;
        const bf16* Wl = smem + 16384 + buf * 8192;
        #pragma unroll
        for (int kk = 0; kk < 2; ++kk) {
            bf16x8 af[4], bfr[4];
            const int kb = kk * 4 + lhi;
            #pragma unroll
            for (int tt = 0; tt < 4; ++tt) {
                const int ra = wr * 64 + tt * 16 + lrow;
                af[tt] = *reinterpret_cast<const bf16x8*>(&Xl[ra * 64 + ((kb ^ (ra & 7)) * 8)]);
            }
            #pragma unroll
            for (int tt = 0; tt < 4; ++tt) {
                const int rb = wc * 64 + tt * 16 + lrow;
                bfr[tt] = *reinterpret_cast<const bf16x8*>(&Wl[rb * 64 + ((kb ^ (rb & 7)) * 8)]);
            }
            #pragma unroll
            for (int i = 0; i < 4; ++i)
                #pragma unroll
                for (int j = 0; j < 4; ++j)
                    acc[i][j] = mfma16(af[i], bfr[j], acc[i][j]);
        }

        asm volatile("s_waitcnt lgkmcnt(0)" ::: "memory");
        __builtin_amdgcn_s_barrier();
        __builtin_amdgcn_sched_barrier(0);
    }

    #pragma unroll
    for (int i = 0; i < 4; ++i) {
        #pragma unroll
        for (int j = 0; j < 4; ++j) {
            const int col = c0 + wc * 64 + j * 16 + lrow;
            const float bb = bias[col];
            #pragma unroll
            for (int rg = 0; rg < 4; ++rg) {
                const int r = r0 + wr * 64 + i * 16 + lhi * 4 + rg;
                float y = acc[i][j][rg] + bb;
                y = y > 0.f ? y : 0.f;
                if (OMODE == 2) {
                    Yf[(size_t)r * 512 + col] = y;
                } else {
                    Y[(size_t)r * 512 + col] = (bf16)y;
                    if (OMODE == 1) {
                        // stash transposed into LDS tile (stride 136)
                        smem[(wc * 64 + j * 16 + lrow) * 136
                             + (wr * 64 + i * 16 + lhi * 4 + rg)] = (bf16)y;
                    }
                }
            }
        }
    }

    if (OMODE == 1) {
        __syncthreads();
        // coalesced write-out: Yt[bi*512 + c0+hr][nn0 + n], 128 h-rows x 128 n
        const int hr = tid >> 1, half = tid & 1;
        const size_t obase = ((size_t)(r0 >> 11) * 512 + c0 + hr) * 2048
                             + (r0 & 2047) + half * 64;
        #pragma unroll
        for (int c = 0; c < 8; ++c) {
            bf16x8 v = *reinterpret_cast<const bf16x8*>(&smem[hr * 136 + half * 64 + c * 8]);
            *reinterpret_cast<bf16x8*>(&Yt[obase + c * 8]) = v;
        }
    }
}

// ---------------- fused attention (R19-exact, ~300us) ----------------
// max==0 softmax (q,k>=0, A in [0,1) => scores<=0): p = exp(x) directly,
// l per-lane, reduced once at epilogue. KVBLK=128 (16 iters). K single-buffered
// (128KB), staged after B1. P_lds stride 128 + 16B-block XOR swizzle.
// s_setprio(1) around both MFMA clusters (T5).
__global__ __launch_bounds__(512, 1)
void attn_kernel(const bf16* __restrict__ Q, const bf16* __restrict__ K,
                 const bf16* __restrict__ Vt, const bf16* __restrict__ V,
                 const float* __restrict__ A, bf16* __restrict__ O)
{
    __shared__ bf16 K_lds[128 * 512];     // 128KB, XOR-swizzled rows, single buffer
    __shared__ bf16 P_lds[64 * 128];      // 16KB, stride 128, XOR-swizzled 16B blocks
    __shared__ float sump_lds[2][64];     // per-strip l partials (epilogue only)

    const int tid = threadIdx.x;
    const int lane = tid & 63, wid = tid >> 6;
    const int wr = wid >> 1, wc = wid & 1;
    const int lrow = lane & 15, lhi = lane >> 4;

    // XCD x handles batches {2x, 2x+1}
    const int id = blockIdx.x;
    const int xcd = id & 7, j = id >> 3;
    const int bb = 2 * xcd + (j >> 5);
    const int n0 = (j & 31) * 64;
    const int srow_base = wr * 16 + lhi * 4;

    const bf16* Kbase  = K + (size_t)bb * SEQ * DH;
    const bf16* Vtbase = Vt + (size_t)bb * DH * SEQ;

    // stage K[0]: 128 rows, 16 per wave
    #pragma unroll
    for (int c = 0; c < 16; ++c) {
        const int row = wid * 16 + c;
        gl_lds16(Kbase + (size_t)row * DH + ((lane ^ (row & 7)) * 8), &K_lds[row * 512]);
    }

    // Q resident: rows n0 + wr*16 + lrow (wc pair loads same rows). 64 VGPR.
    bf16x8 qf[16];
    {
        const bf16* qp = Q + (size_t)(bb * SEQ + n0 + wr * 16 + lrow) * DH + lhi * 8;
        #pragma unroll
        for (int kk = 0; kk < 16; ++kk)
            qf[kk] = *reinterpret_cast<const bf16x8*>(qp + kk * 32);
    }

    float l_part[4] = {};      // per-lane denominator partials (rows srow_base+rg)
    f32x4 acc[4][4] = {};      // [q-row-tile][h-tile of this wave's 64-col slice]

    __syncthreads();  // K[0] drained + published

    for (int it = 0; it < 16; ++it) {
        const int m0 = it * 128;

        // A for this iter (consumed after QK^T). 16 loads.
        float av[16];  // [sc*4 + rg]
        {
            const float* ap = A + ((size_t)bb * SEQ + n0 + srow_base) * SEQ + m0 + wc * 64 + lrow;
            #pragma unroll
            for (int sc = 0; sc < 4; ++sc)
                #pragma unroll
                for (int rg = 0; rg < 4; ++rg)
                    av[sc * 4 + rg] = ap[(size_t)rg * SEQ + sc * 16];
        }

        // ---- QK^T: S[16 rows x 64-col strip] from K_lds (4 indep chains) ----
        f32x4 s[4] = {};
        {
            __builtin_amdgcn_s_setprio(1);
            #pragma unroll
            for (int kk = 0; kk < 16; ++kk) {
                const int ks = kk * 4 + lhi;
                #pragma unroll
                for (int sc = 0; sc < 4; ++sc) {
                    const int kr = wc * 64 + sc * 16 + lrow;
                    bf16x8 kf = *reinterpret_cast<const bf16x8*>(
                        &K_lds[kr * 512 + ((ks ^ (kr & 7)) * 8)]);
                    s[sc] = mfma16(qf[kk], kf, s[sc]);
                }
            }
            __builtin_amdgcn_s_setprio(0);
        }

        // ---- p = exp(score * -A) (max==0); P -> LDS (swizzled); l accumulate ----
        #pragma unroll
        for (int sc = 0; sc < 4; ++sc) {
            #pragma unroll
            for (int rg = 0; rg < 4; ++rg) {
                const float p = __expf(s[sc][rg] * (-av[sc * 4 + rg]));
                const int row = srow_base + rg;
                const int blk = wc * 8 + sc * 2 + (lrow >> 3);   // col>>3
                P_lds[row * 128 + ((blk ^ (row & 7)) * 8) + (lrow & 7)] = (bf16)p;
                l_part[rg] += p;
            }
        }

        // B1: lgkm-only — P writes + K reads retired; VMEM stays in flight
        asm volatile("s_waitcnt lgkmcnt(0)" ::: "memory");
        __builtin_amdgcn_s_barrier();
        __builtin_amdgcn_sched_barrier(0);

        // stage K[it+1] into the SAME buffer (WAR-safe: all K reads retired at
        // B1). Completion: vf loads below issued AFTER these; PV's vf wait
        // (in-order vmcnt) forces stage completion; B2 publishes block-wide.
        if (it + 1 < 16) {
            #pragma unroll
            for (int c = 0; c < 16; ++c) {
                const int row = wid * 16 + c;
                gl_lds16(Kbase + (size_t)(m0 + 128 + row) * DH + ((lane ^ (row & 7)) * 8),
                         &K_lds[row * 512]);
            }
        }

        // ---- PV: P (LDS, swizzled) x Vt (JIT regs, per-kc double-buffer) ----
        {
            const bf16* vp = Vtbase + (size_t)(wid * 64 + lrow) * SEQ + m0 + lhi * 8;
            bf16x8 vfk[2][4];
            #pragma unroll
            for (int ht = 0; ht < 4; ++ht)
                vfk[0][ht] = *reinterpret_cast<const bf16x8*>(vp + (size_t)(ht * 16) * SEQ);
            #pragma unroll
            for (int kc = 0; kc < 4; ++kc) {
                if (kc + 1 < 4) {
                    #pragma unroll
                    for (int ht = 0; ht < 4; ++ht)
                        vfk[(kc + 1) & 1][ht] = *reinterpret_cast<const bf16x8*>(
                            vp + (size_t)(ht * 16) * SEQ + (kc + 1) * 32);
                }
                __builtin_amdgcn_s_setprio(1);
                #pragma unroll
                for (int t = 0; t < 4; ++t) {
                    const int prow = t * 16 + lrow;
                    const bf16x8 pf = *reinterpret_cast<const bf16x8*>(
                        &P_lds[prow * 128 + (((kc * 4 + lhi) ^ (prow & 7)) * 8)]);
                    #pragma unroll
                    for (int ht = 0; ht < 4; ++ht)
                        acc[t][ht] = mfma16(pf, vfk[kc & 1][ht], acc[t][ht]);
                }
                __builtin_amdgcn_s_setprio(0);
            }
        }

        // B2: lgkm-only — P reads retired (WAR for next writes); K[it+1] stage
        // complete per-wave (via vf in-order waits) -> published block-wide.
        asm volatile("s_waitcnt lgkmcnt(0)" ::: "memory");
        __builtin_amdgcn_s_barrier();
        __builtin_amdgcn_sched_barrier(0);
    }

    // ---- epilogue: reduce l over the 16 lrow lanes per strip, combine strips ----
    #pragma unroll
    for (int rg = 0; rg < 4; ++rg) {
        float sv = l_part[rg];
        sv += __shfl_xor(sv, 1);
        sv += __shfl_xor(sv, 2);
        sv += __shfl_xor(sv, 4);
        sv += __shfl_xor(sv, 8);
        if (lrow == 0) sump_lds[wc][srow_base + rg] = sv;
    }
    __syncthreads();

    // ---- /l, +V, store ----
    #pragma unroll
    for (int t = 0; t < 4; ++t) {
        #pragma unroll
        for (int rg = 0; rg < 4; ++rg) {
            const int row = t * 16 + lhi * 4 + rg;
            const float inv = 1.f / (sump_lds[0][row] + sump_lds[1][row]);
            const size_t rbase = (size_t)(bb * SEQ + n0 + row) * DH;
            #pragma unroll
            for (int ht = 0; ht < 4; ++ht) {
                const int col = wid * 64 + ht * 16 + lrow;
                const float vv = (float)V[rbase + col];
                O[rbase + col] = (bf16)(acc[t][ht][rg] * inv + vv);
            }
        }
    }
}

extern "C" void kernel_launch(void* const* d_in, const int* in_sizes, int n_in,
                              void* d_out, int out_size, void* d_ws, size_t ws_size,
                              hipStream_t stream) {
    const float* A    = (const float*)d_in[0];
    const float* h    = (const float*)d_in[1];
    const float* Wv1  = (const float*)d_in[2];
    const float* bv1  = (const float*)d_in[3];
    const float* Wv2  = (const float*)d_in[4];
    const float* bv2  = (const float*)d_in[5];
    const float* Wk   = (const float*)d_in[6];   // NOTE: Wk before Wq in dict order
    const float* bk   = (const float*)d_in[7];
    const float* Wq   = (const float*)d_in[8];
    const float* bq   = (const float*)d_in[9];
    const float* Wout = (const float*)d_in[10];
    const float* bout = (const float*)d_in[11];
    float* out = (float*)d_out;

    char* ws = (char*)d_ws;
    const size_t SZ = (size_t)ROWS * 512 * sizeof(bf16);  // 33.5 MB
    bf16* hb   = (bf16*)(ws + 0 * SZ);  // h bf16; dead after tqk -> vtb aliases it
    bf16* tb   = (bf16*)(ws + 1 * SZ);  // t; dead after v-GEMM -> ob aliases it
    bf16* qb   = (bf16*)(ws + 2 * SZ);
    bf16* kb   = (bf16*)(ws + 3 * SZ);
    bf16* vb   = (bf16*)(ws + 4 * SZ);
    bf16* wbase = (bf16*)(ws + 5 * SZ); // 5 x 512KB bf16 weights
    bf16* Wv1t  = wbase + 0 * 262144;
    bf16* Wv2t  = wbase + 1 * 262144;
    bf16* Wqt   = wbase + 2 * 262144;
    bf16* Wkt   = wbase + 3 * 262144;
    bf16* Woutt = wbase + 4 * 262144;
    bf16* vtb = hb;  // v transposed [B][H][N]; hb dead after gemm_tqk
    bf16* ob  = tb;  // attention output; tb dead after v-GEMM

    cvt_all_kernel<<<9216, 256, 0, stream>>>(h, Wv1, Wv2, Wq, Wk, Wout, hb, wbase);

    // t, q, k in ONE launch (X panel staged once per weight; L2-hot for w>=1)
    gemm_tqk_kernel<<<1024, 256, 0, stream>>>(hb, Wv1t, Wqt, Wkt, bv1, bq, bk,
                                              tb, qb, kb);

    // v = relu(t @ Wv2 + b), plus coalesced transposed copy vtb
    gemm_relu_kernel<1><<<1024, 256, 0, stream>>>(tb, Wv2t, bv2, vb, vtb, nullptr);

    attn_kernel<<<dim3(512), 512, 0, stream>>>(qb, kb, vtb, vb, A, ob);

    gemm_relu_kernel<2><<<1024, 256, 0, stream>>>(ob, Woutt, bout, nullptr, nullptr, out);
}